// Round 6
// baseline (633.789 us; speedup 1.0000x reference)
//
#include <hip/hip_runtime.h>
#include <hip/hip_bf16.h>
#include <stdint.h>

typedef unsigned short ushort_t;
typedef short short8 __attribute__((ext_vector_type(8)));
typedef unsigned short ushortx8 __attribute__((ext_vector_type(8)));
typedef float floatx4 __attribute__((ext_vector_type(4)));

// relaxed barrier: HW barrier + compiler-level memory fence, but NO implicit waitcnt
// (__syncthreads emits s_waitcnt vmcnt(0) — the documented m97 barrier-drain stall).
#define SBAR() asm volatile("s_barrier" ::: "memory")

__device__ __forceinline__ float b2f(ushort_t u) {
    return __uint_as_float(((unsigned int)u) << 16);
}
__device__ __forceinline__ ushort_t f2bf(float f) {
    unsigned int u = __float_as_uint(f);
    unsigned int r = u + 0x7FFFu + ((u >> 16) & 1u);
    return (ushort_t)(r >> 16);
}
// packed f32->bf16 RNE (identical rounding to f2bf for finite values); src0 -> low half
__device__ __forceinline__ unsigned int cvtpk(float lo, float hi) {
    unsigned int r;
    asm("v_cvt_pk_bf16_f32 %0, %1, %2" : "=v"(r) : "v"(lo), "v"(hi));
    return r;
}
// async global->LDS, 16B per lane; lds base wave-uniform, lanes land at base+lane*16
__device__ __forceinline__ void gll16(const void* g, void* l) {
    __builtin_amdgcn_global_load_lds((const __attribute__((address_space(1))) unsigned int*)g,
                                     (__attribute__((address_space(3))) unsigned int*)l,
                                     16, 0, 0);
}

// ---------------- transpose + downcast: out_bf16[n*K + k] = in_f32[k*N + n], batched ----
__global__ void transpose_kernel(const float* __restrict__ in, ushort_t* __restrict__ out,
                                 int K, int N) {
    __shared__ float tile[32][33];
    in += (long)blockIdx.z * K * N;
    out += (long)blockIdx.z * K * N;
    int k0 = blockIdx.x * 32, n0 = blockIdx.y * 32;
    int x = threadIdx.x, y = threadIdx.y;  // (32, 8)
#pragma unroll
    for (int i = 0; i < 4; i++)
        tile[y + 8 * i][x] = in[(long)(k0 + y + 8 * i) * N + n0 + x];
    __syncthreads();
#pragma unroll
    for (int i = 0; i < 4; i++)
        out[(long)(n0 + y + 8 * i) * K + k0 + x] = f2bf(tile[x][y + 8 * i]);
}

// concat bias for fused QKV
__global__ void concat_bias_kernel(const float* __restrict__ bq, const float* __restrict__ bk,
                                   const float* __restrict__ bv, float* __restrict__ dst) {
    int i = blockIdx.x * 256 + threadIdx.x;
    dst[i] = i < 1024 ? bq[i] : (i < 2048 ? bk[i - 1024] : bv[i - 2048]);
}

// ---------------- LayerNorm over C=1024, f32 in -> bf16 out ----------------
__global__ __launch_bounds__(256) void ln_kernel(const float* __restrict__ in,
                                                 ushort_t* __restrict__ out,
                                                 const float* __restrict__ g,
                                                 const float* __restrict__ b) {
    long row = blockIdx.x;
    int tid = threadIdx.x;
    float4 v4 = *((const float4*)(in + row * 1024) + tid);
    float v[4] = {v4.x, v4.y, v4.z, v4.w};
    float s1 = v[0] + v[1] + v[2] + v[3];
    float s2 = v[0] * v[0] + v[1] * v[1] + v[2] * v[2] + v[3] * v[3];
#pragma unroll
    for (int m = 32; m >= 1; m >>= 1) {
        s1 += __shfl_xor(s1, m);
        s2 += __shfl_xor(s2, m);
    }
    __shared__ float r1[4], r2[4];
    int w = tid >> 6;
    if ((tid & 63) == 0) { r1[w] = s1; r2[w] = s2; }
    __syncthreads();
    s1 = r1[0] + r1[1] + r1[2] + r1[3];
    s2 = r2[0] + r2[1] + r2[2] + r2[3];
    float mu = s1 * (1.0f / 1024.0f);
    float var = s2 * (1.0f / 1024.0f) - mu * mu;
    float inv = rsqrtf(var + 1e-5f);
    float y[4];
#pragma unroll
    for (int i = 0; i < 4; i++)
        y[i] = (v[i] - mu) * inv * g[tid * 4 + i] + b[tid * 4 + i];
    unsigned int lo = (unsigned int)f2bf(y[0]) | ((unsigned int)f2bf(y[1]) << 16);
    unsigned int hi = (unsigned int)f2bf(y[2]) | ((unsigned int)f2bf(y[3]) << 16);
    *(uint2*)(out + row * 1024 + tid * 4) = make_uint2(lo, hi);
}

// ------- 128x128 MFMA GEMM v2: 3-buffer depth-2 counted-vmcnt pipeline + T2 swizzle ----
// 256 threads = 4 waves; per-wave 64x64 out; LDS 3 bufs x (A 8K + B 8K) = 48KB -> 3 blocks/CU.
// Iter t: stage K-tile t+2 into buf (t+2)%3 (last read at t-1; separated by t's top barrier),
// compute tile t from buf t%3, then vmcnt(4) (drains exactly tile t+1's 4 loads — issued a
// full iteration earlier, so latency-covered; never vmcnt(0) in steady state) + raw s_barrier.
// LDS tiles [row][32] with both-sides XOR swizzle: 16B slot c holds global slot
// c ^ (((row&15)>>1)&3) via pre-swizzled global source (gll16 dest is linear); reads
// compensate with quad ^ ((ln>>1)&3). Same pattern as attn (measured 0 conflicts).
// MODE 0: off=(gm>>11)*cBatch+(gm&2047)*ldc+gn, +bias/relu/resid.
// MODE 2 (QKV): n<1024 q, n<2048 k (contig), n>=2048 v^T [B,H,DH,T]. (verbatim from R2)
template <typename OutT, int RELU, int MODE>
__device__ __forceinline__ void gemm128(
    const ushort_t* __restrict__ A, int lda,
    const ushort_t* __restrict__ Bt, int ldb, int K,
    OutT* __restrict__ C, long cBatch, int ldc,
    const float* __restrict__ bias, const float* __restrict__ resid,
    ushort_t* As, ushort_t* Bs, int mT, int nT) {
    int m0 = mT * 128, n0 = nT * 128;
    int tid = threadIdx.x, lane = tid & 63, w = tid >> 6;
    int ln = lane & 15, quad = lane >> 4;
    int wr = w >> 1, wc = w & 1;
    int lr = lane >> 2, lq = lane & 3;
    int ssw = (lr >> 1) & 3, rsw = (ln >> 1) & 3;

    // staging sources (pre-swizzled col slot) and LDS segment bases
    const ushort_t* src[4];
    ushort_t* dstb[4];
#pragma unroll
    for (int i = 0; i < 4; i++) {
        int id = w * 4 + i;  // 0..15: 8 A-segments then 8 B-segments (16 rows each)
        int blk = id & 7;
        int row = blk * 16 + lr;
        src[i] = (id < 8 ? A + (long)(m0 + row) * lda
                         : Bt + (long)(n0 + row) * ldb) + ((lq ^ ssw) << 3);
        dstb[i] = (id < 8 ? As : Bs) + blk * 512;
    }
    auto stage = [&](int t, int buf) {
#pragma unroll
        for (int i = 0; i < 4; i++) gll16(src[i] + t * 32, dstb[i] + buf * 4096);
    };

    floatx4 acc[4][4];
#pragma unroll
    for (int a = 0; a < 4; a++)
#pragma unroll
        for (int bb = 0; bb < 4; bb++) acc[a][bb] = floatx4{0, 0, 0, 0};

    int NT = K >> 5;
    stage(0, 0);
    stage(1, 1);
    asm volatile("s_waitcnt vmcnt(4)" ::: "memory");  // drain tile 0 only
    SBAR();

    int cur = 0, bst = 2;
    auto body = [&](int t, int doStage, int vm) {
        if (doStage) stage(t + 2, bst);
        const ushort_t* Ab = As + cur * 4096;
        const ushort_t* Bb = Bs + cur * 4096;
        short8 af[4], bf[4];
#pragma unroll
        for (int j = 0; j < 4; j++) {
            af[j] = *(const short8*)(Ab + (wr * 64 + j * 16 + ln) * 32 + ((quad ^ rsw) << 3));
            bf[j] = *(const short8*)(Bb + (wc * 64 + j * 16 + ln) * 32 + ((quad ^ rsw) << 3));
        }
#pragma unroll
        for (int a = 0; a < 4; a++)
#pragma unroll
            for (int bb = 0; bb < 4; bb++)
                acc[a][bb] = __builtin_amdgcn_mfma_f32_16x16x32_bf16(af[a], bf[bb], acc[a][bb], 0, 0, 0);
        if (vm == 4)
            asm volatile("s_waitcnt vmcnt(4)" ::: "memory");  // publish tile t+1
        else if (vm == 0)
            asm volatile("s_waitcnt vmcnt(0)" ::: "memory");  // tail: publish last tile
        SBAR();
        cur = cur == 2 ? 0 : cur + 1;
        bst = bst == 2 ? 0 : bst + 1;
    };
    for (int t = 0; t < NT - 2; ++t) body(t, 1, 4);
    body(NT - 2, 0, 0);
    body(NT - 1, 0, -1);

    // epilogue (verbatim from the R2-proven version)
#pragma unroll
    for (int bb = 0; bb < 4; bb++) {
        int gn = n0 + wc * 64 + bb * 16 + ln;
        float bv = bias ? bias[gn] : 0.0f;
#pragma unroll
        for (int a = 0; a < 4; a++) {
#pragma unroll
            for (int r = 0; r < 4; r++) {
                int gm = m0 + wr * 64 + a * 16 + quad * 4 + r;
                float val = acc[a][bb][r] + bv;
                if (RELU) val = fmaxf(val, 0.0f);
                if constexpr (MODE == 2) {
                    int gnl = gn & 1023;
                    long off;
                    if (gn < 2048)  // q or k: [2][B,T,1024] contiguous
                        off = (long)(gn >> 10) * 8388608 + (long)(gm >> 11) * 2097152 +
                              (long)(gm & 2047) * 1024 + gnl;
                    else  // v transposed: [B,H,64,2048] at +16M elems
                        off = 16777216L +
                              ((((long)(gm >> 11)) * 16 + (gnl >> 6)) * 64 + (gnl & 63)) * 2048 +
                              (gm & 2047);
                    C[off] = (OutT)f2bf(val);
                } else {
                    long off = (long)(gm >> 11) * cBatch + (long)(gm & 2047) * ldc + gn;
                    if (resid) val += resid[off];
                    if constexpr (sizeof(OutT) == 2)
                        C[off] = (OutT)f2bf(val);
                    else
                        C[off] = (OutT)val;
                }
            }
        }
    }
}

// T1 bijective XCD swizzle over a 1D grid (nwg % 8 == 0 for all our grids).
// Consecutive wg in a chunk share nT (B-panel stays L2-resident per XCD).
__device__ __forceinline__ int xcd_swz(int flat, int nwg) {
    return (flat & 7) * (nwg >> 3) + (flat >> 3);
}

__global__ __launch_bounds__(256, 3) void gemm128_qkv_kernel(
    const ushort_t* __restrict__ A, const ushort_t* __restrict__ Bt,
    ushort_t* __restrict__ C, const float* __restrict__ bias) {
    __shared__ ushort_t As[3 * 4096];
    __shared__ ushort_t Bs[3 * 4096];
    int wg = xcd_swz(blockIdx.x, gridDim.x);
    gemm128<ushort_t, 0, 2>(A, 1024, Bt, 1024, 1024, C, 0, 0, bias, nullptr,
                            As, Bs, wg & 63, wg >> 6);
}

__global__ __launch_bounds__(256, 3) void gemm128_relu_kernel(
    const ushort_t* __restrict__ A, int lda, const ushort_t* __restrict__ Bt, int ldb, int K,
    ushort_t* __restrict__ C, long cBatch, int ldc, const float* __restrict__ bias) {
    __shared__ ushort_t As[3 * 4096];
    __shared__ ushort_t Bs[3 * 4096];
    int wg = xcd_swz(blockIdx.x, gridDim.x);
    gemm128<ushort_t, 1, 0>(A, lda, Bt, ldb, K, C, cBatch, ldc, bias, nullptr,
                            As, Bs, wg & 63, wg >> 6);
}

__global__ __launch_bounds__(256, 3) void gemm128_f32_kernel(
    const ushort_t* __restrict__ A, int lda, const ushort_t* __restrict__ Bt, int ldb, int K,
    float* __restrict__ C, long cBatch, int ldc,
    const float* __restrict__ bias, const float* __restrict__ resid) {
    __shared__ ushort_t As[3 * 4096];
    __shared__ ushort_t Bs[3 * 4096];
    int wg = xcd_swz(blockIdx.x, gridDim.x);
    gemm128<float, 0, 0>(A, lda, Bt, ldb, K, C, cBatch, ldc, bias, resid,
                         As, Bs, wg & 63, wg >> 6);
}

// ---------------- MFMA flash attention v6: LDS-free P via K-row permutation ----------------
// (unchanged from R2: 0 bank conflicts, 32KB LDS; see R2 notes)
__global__ __launch_bounds__(512, 4) void attn_kernel(
    const ushort_t* __restrict__ q, const ushort_t* __restrict__ k,
    const ushort_t* __restrict__ vt, ushort_t* __restrict__ o) {
    __shared__ ushort_t Klds[2 * 4096];       // [buf][s-half][kv slot 64][32]
    __shared__ ushort_t Vlds[2 * 4096];       // [buf][kv-half][d row 64][32]
    int flat = blockIdx.x;
    int bh = (flat & 7) * 8 + (flat >> 6);
    int xt = (flat >> 3) & 7;
    int b = bh >> 4, h = bh & 15;
    int t0 = xt * 256;
    int tid = threadIdx.x, lane = tid & 63, w = tid >> 6;
    int ln = lane & 15, quad = lane >> 4;
    int lr = lane >> 2, lq = lane & 3;
    int bsrc = (lane & 48) + ((lane >> 4) << 2);  // broadcast src: ln' = quad*4+r
    int rsw = (ln >> 1) & 3;                      // read-side K/V slot swizzle
    int ssw = (lr >> 1) & 3;                      // stage-side (source col) swizzle

    const ushort_t* qbase = q + ((long)b * 2048 + t0 + w * 32) * 1024 + h * 64;
    short8 qf[2][2];
#pragma unroll
    for (int sub = 0; sub < 2; sub++)
#pragma unroll
        for (int s = 0; s < 2; s++) {
            ushortx8 t = *(const ushortx8*)(qbase + (long)(sub * 16 + ln) * 1024 + s * 32 + quad * 8);
#pragma unroll
            for (int j = 0; j < 8; j++) qf[sub][s][j] = (short)f2bf(b2f(t[j]) * 8.0f);
        }

    floatx4 O[2][4];
    float m_i[2] = {-1e30f, -1e30f}, l_i[2] = {0.0f, 0.0f};
#pragma unroll
    for (int sub = 0; sub < 2; sub++)
#pragma unroll
        for (int i = 0; i < 4; i++) O[sub][i] = floatx4{0, 0, 0, 0};

    long krow0 = (long)b * 2048 * 1024 + h * 64;
    const ushort_t* vbase = vt + (long)bh * 64 * 2048;

    auto stage = [&](int kv0, int buf) {
#pragma unroll
        for (int i = 0; i < 2; i++) {
            int id = w * 2 + i;  // 0..15: 8 K-quarters then 8 V-quarters
            int s = (id >> 2) & 1, qt = id & 3;
            int cs = ((lq ^ ssw) << 3);
            if (id < 8) {
                int prow = ((qt >> 1) << 5) + ((lr >> 2) << 3) + ((qt & 1) << 2) + (lr & 3);
                gll16(k + krow0 + (long)(kv0 + prow) * 1024 + s * 32 + cs,
                      Klds + buf * 4096 + s * 2048 + qt * 512);
            } else {
                int row = qt * 16 + lr;  // d row
                gll16(vbase + (long)row * 2048 + kv0 + s * 32 + cs,
                      Vlds + buf * 4096 + s * 2048 + qt * 512);
            }
        }
    };

    stage(0, 0);
    int cur = 0;
    for (int t32 = 0; t32 < 32; t32++, cur ^= 1) {
        __syncthreads();
        if (t32 < 31) stage((t32 + 1) * 64, cur ^ 1);
        const ushort_t* Kb = Klds + cur * 4096;
        const ushort_t* Vb = Vlds + cur * 4096;

        floatx4 Z[2][4];
#pragma unroll
        for (int sub = 0; sub < 2; sub++)
#pragma unroll
            for (int nc = 0; nc < 4; nc++) Z[sub][nc] = floatx4{0, 0, 0, 0};
#pragma unroll
        for (int s = 0; s < 2; s++)
#pragma unroll
            for (int nc = 0; nc < 4; nc++) {
                short8 kf = *(const short8*)(Kb + s * 2048 + (nc * 16 + ln) * 32 + ((quad ^ rsw) << 3));
                Z[0][nc] = __builtin_amdgcn_mfma_f32_16x16x32_bf16(kf, qf[0][s], Z[0][nc], 0, 0, 0);
                Z[1][nc] = __builtin_amdgcn_mfma_f32_16x16x32_bf16(kf, qf[1][s], Z[1][nc], 0, 0, 0);
            }

        float alpha[2];
        short8 pf[2][2];
#pragma unroll
        for (int sub = 0; sub < 2; sub++) {
            float mx = -1e30f;
#pragma unroll
            for (int nc = 0; nc < 4; nc++)
#pragma unroll
                for (int r = 0; r < 4; r++) mx = fmaxf(mx, Z[sub][nc][r]);
            mx = fmaxf(mx, __shfl_xor(mx, 16));
            mx = fmaxf(mx, __shfl_xor(mx, 32));
            float nm = fmaxf(m_i[sub], mx);
            alpha[sub] = __expf(m_i[sub] - nm);
            m_i[sub] = nm;
            float rs = 0.0f;
#pragma unroll
            for (int s = 0; s < 2; s++) {
                float a0 = __expf(Z[sub][2 * s][0] - nm), a1 = __expf(Z[sub][2 * s][1] - nm);
                float a2 = __expf(Z[sub][2 * s][2] - nm), a3 = __expf(Z[sub][2 * s][3] - nm);
                float b0 = __expf(Z[sub][2 * s + 1][0] - nm), b1 = __expf(Z[sub][2 * s + 1][1] - nm);
                float b2 = __expf(Z[sub][2 * s + 1][2] - nm), b3 = __expf(Z[sub][2 * s + 1][3] - nm);
                rs += ((a0 + a1) + (a2 + a3)) + ((b0 + b1) + (b2 + b3));
                union { unsigned int u[4]; short8 v; } pu;
                pu.u[0] = cvtpk(a0, a1);
                pu.u[1] = cvtpk(a2, a3);
                pu.u[2] = cvtpk(b0, b1);
                pu.u[3] = cvtpk(b2, b3);
                pf[sub][s] = pu.v;
            }
            rs += __shfl_xor(rs, 16);
            rs += __shfl_xor(rs, 32);
            l_i[sub] = l_i[sub] * alpha[sub] + rs;
        }
#pragma unroll
        for (int sub = 0; sub < 2; sub++)
#pragma unroll
            for (int r = 0; r < 4; r++) {
                float ar = __shfl(alpha[sub], bsrc + r);
#pragma unroll
                for (int dc = 0; dc < 4; dc++) O[sub][dc][r] *= ar;
            }
#pragma unroll
        for (int s = 0; s < 2; s++)
#pragma unroll
            for (int dc = 0; dc < 4; dc++) {
                short8 vf = *(const short8*)(Vb + s * 2048 + (dc * 16 + ln) * 32 + ((quad ^ rsw) << 3));
                O[0][dc] = __builtin_amdgcn_mfma_f32_16x16x32_bf16(pf[0][s], vf, O[0][dc], 0, 0, 0);
                O[1][dc] = __builtin_amdgcn_mfma_f32_16x16x32_bf16(pf[1][s], vf, O[1][dc], 0, 0, 0);
            }
    }
#pragma unroll
    for (int sub = 0; sub < 2; sub++)
#pragma unroll
        for (int r = 0; r < 4; r++) {
            float inv = 1.0f / __shfl(l_i[sub], bsrc + r);
            int t = t0 + w * 32 + sub * 16 + quad * 4 + r;
            ushort_t* orow = o + ((long)b * 2048 + t) * 1024 + h * 64;
#pragma unroll
            for (int dc = 0; dc < 4; dc++) orow[dc * 16 + ln] = f2bf(O[sub][dc][r] * inv);
        }
}

extern "C" void kernel_launch(void* const* d_in, const int* in_sizes, int n_in,
                              void* d_out, int out_size, void* d_ws, size_t ws_size,
                              hipStream_t stream) {
    const float* x   = (const float*)d_in[0];
    const float* Wq  = (const float*)d_in[1];
    const float* bq  = (const float*)d_in[2];
    const float* Wk  = (const float*)d_in[3];
    const float* bk  = (const float*)d_in[4];
    const float* Wv  = (const float*)d_in[5];
    const float* bv  = (const float*)d_in[6];
    const float* Wo  = (const float*)d_in[7];
    const float* bo  = (const float*)d_in[8];
    const float* g1  = (const float*)d_in[9];
    const float* be1 = (const float*)d_in[10];
    const float* g2  = (const float*)d_in[11];
    const float* be2 = (const float*)d_in[12];
    const float* W1  = (const float*)d_in[13];
    const float* b1  = (const float*)d_in[14];
    const float* W2  = (const float*)d_in[15];
    const float* b2  = (const float*)d_in[16];
    float* out = (float*)d_out;

    const long MB = 1 << 20;
    char* w = (char*)d_ws;
    ushort_t* xn  = (ushort_t*)(w);            // [8192,1024] bf16; reused as attn output o
    float*    x2  = (float*)(w + 16 * MB);     // [8192,1024] f32 (first 12KB doubles as biasCat)
    ushort_t* qb  = (ushort_t*)(w + 48 * MB);  // [B,T,C] bf16; kb,vtb contiguous after
    ushort_t* kb  = (ushort_t*)(w + 64 * MB);  // [B,T,C] bf16
    ushort_t* vtb = (ushort_t*)(w + 80 * MB);  // [B,H,DH,T] bf16
    ushort_t* xn2 = qb;                        // alias (qb dead after attention)
    ushort_t* h1  = (ushort_t*)(w + 64 * MB);  // [8192,2048] bf16 (kb/vtb dead)
    ushort_t* WqT = (ushort_t*)(w + 96 * MB);  // [H,DH,C]; WqT/WkT/WvT contiguous = QKV B^T
    ushort_t* WkT = (ushort_t*)(w + 98 * MB);
    ushort_t* WvT = (ushort_t*)(w + 100 * MB);
    ushort_t* WoT = (ushort_t*)(w + 102 * MB); // [C,C]^T
    ushort_t* W1T = (ushort_t*)(w + 104 * MB); // [DFF,C]
    ushort_t* W2T = (ushort_t*)(w + 112 * MB); // [C,DFF]  (ends at 120 MB)
    float* biasCat = x2;                       // 3072 floats, dead before Wo writes x2

    dim3 tb(32, 8);
    transpose_kernel<<<dim3(32, 2, 16), tb, 0, stream>>>(Wq, WqT, 1024, 64);
    transpose_kernel<<<dim3(32, 2, 16), tb, 0, stream>>>(Wk, WkT, 1024, 64);
    transpose_kernel<<<dim3(32, 2, 16), tb, 0, stream>>>(Wv, WvT, 1024, 64);
    transpose_kernel<<<dim3(32, 32, 1), tb, 0, stream>>>(Wo, WoT, 1024, 1024);
    transpose_kernel<<<dim3(32, 128, 1), tb, 0, stream>>>(W1, W1T, 1024, 4096);
    transpose_kernel<<<dim3(128, 32, 1), tb, 0, stream>>>(W2, W2T, 4096, 1024);
    concat_bias_kernel<<<12, 256, 0, stream>>>(bq, bk, bv, biasCat);

    ln_kernel<<<8192, 256, 0, stream>>>(x, xn, g1, be1);
    // fused QKV: q,k -> [2][B,T,C] at qb; v -> [B,H,DH,T] at vtb (= qb + 16M elems)
    gemm128_qkv_kernel<<<1536, 256, 0, stream>>>(xn, WqT, qb, biasCat);
    attn_kernel<<<512, 512, 0, stream>>>(qb, kb, vtb, xn /* o */);
    // x2 = x + o @ Wo + bo   (fp32 out)
    gemm128_f32_kernel<<<512, 256, 0, stream>>>(xn, 1024, WoT, 1024, 1024,
                                                x2, 2048L * 1024, 1024, bo, x);
    ln_kernel<<<8192, 256, 0, stream>>>((const float*)x2, xn2, g2, be2);
    // FFN in two DFF=2048 halves (ws budget)
    gemm128_relu_kernel<<<1024, 256, 0, stream>>>(
        xn2, 1024, W1T, 1024, 1024, h1, 2048L * 2048, 2048, b1);
    gemm128_f32_kernel<<<512, 256, 0, stream>>>(
        h1, 2048, W2T, 4096, 2048, out, 2048L * 1024, 1024, b2, x2);
    gemm128_relu_kernel<<<1024, 256, 0, stream>>>(
        xn2, 1024, W1T + 2048L * 1024, 1024, 1024, h1, 2048L * 2048, 2048, b1 + 2048);
    gemm128_f32_kernel<<<512, 256, 0, stream>>>(
        h1, 2048, W2T + 2048, 4096, 2048, out, 2048L * 1024, 1024, nullptr, out);
}

// Round 7
// 569.565 us; speedup vs baseline: 1.1128x; 1.1128x over previous
//
#include <hip/hip_runtime.h>
#include <hip/hip_bf16.h>
#include <stdint.h>

typedef unsigned short ushort_t;
typedef short short8 __attribute__((ext_vector_type(8)));
typedef unsigned short ushortx8 __attribute__((ext_vector_type(8)));
typedef float floatx4 __attribute__((ext_vector_type(4)));

// raw barrier: HW barrier + compiler memory fence (no scheduler pinning, no implicit waitcnt)
#define SBAR() asm volatile("s_barrier" ::: "memory")

__device__ __forceinline__ float b2f(ushort_t u) {
    return __uint_as_float(((unsigned int)u) << 16);
}
__device__ __forceinline__ ushort_t f2bf(float f) {
    unsigned int u = __float_as_uint(f);
    unsigned int r = u + 0x7FFFu + ((u >> 16) & 1u);
    return (ushort_t)(r >> 16);
}
// packed f32->bf16 RNE (identical rounding to f2bf for finite values); src0 -> low half
__device__ __forceinline__ unsigned int cvtpk(float lo, float hi) {
    unsigned int r;
    asm("v_cvt_pk_bf16_f32 %0, %1, %2" : "=v"(r) : "v"(lo), "v"(hi));
    return r;
}
// async global->LDS, 16B per lane; lds base wave-uniform, lanes land at base+lane*16
__device__ __forceinline__ void gll16(const void* g, void* l) {
    __builtin_amdgcn_global_load_lds((const __attribute__((address_space(1))) unsigned int*)g,
                                     (__attribute__((address_space(3))) unsigned int*)l,
                                     16, 0, 0);
}

// ---------------- transpose + downcast: out_bf16[n*K + k] = in_f32[k*N + n], batched ----
__global__ void transpose_kernel(const float* __restrict__ in, ushort_t* __restrict__ out,
                                 int K, int N) {
    __shared__ float tile[32][33];
    in += (long)blockIdx.z * K * N;
    out += (long)blockIdx.z * K * N;
    int k0 = blockIdx.x * 32, n0 = blockIdx.y * 32;
    int x = threadIdx.x, y = threadIdx.y;  // (32, 8)
#pragma unroll
    for (int i = 0; i < 4; i++)
        tile[y + 8 * i][x] = in[(long)(k0 + y + 8 * i) * N + n0 + x];
    __syncthreads();
#pragma unroll
    for (int i = 0; i < 4; i++)
        out[(long)(n0 + y + 8 * i) * K + k0 + x] = f2bf(tile[x][y + 8 * i]);
}

// concat bias for fused QKV
__global__ void concat_bias_kernel(const float* __restrict__ bq, const float* __restrict__ bk,
                                   const float* __restrict__ bv, float* __restrict__ dst) {
    int i = blockIdx.x * 256 + threadIdx.x;
    dst[i] = i < 1024 ? bq[i] : (i < 2048 ? bk[i - 1024] : bv[i - 2048]);
}

// ---------------- LayerNorm over C=1024, f32 in -> bf16 out ----------------
__global__ __launch_bounds__(256) void ln_kernel(const float* __restrict__ in,
                                                 ushort_t* __restrict__ out,
                                                 const float* __restrict__ g,
                                                 const float* __restrict__ b) {
    long row = blockIdx.x;
    int tid = threadIdx.x;
    float4 v4 = *((const float4*)(in + row * 1024) + tid);
    float v[4] = {v4.x, v4.y, v4.z, v4.w};
    float s1 = v[0] + v[1] + v[2] + v[3];
    float s2 = v[0] * v[0] + v[1] * v[1] + v[2] * v[2] + v[3] * v[3];
#pragma unroll
    for (int m = 32; m >= 1; m >>= 1) {
        s1 += __shfl_xor(s1, m);
        s2 += __shfl_xor(s2, m);
    }
    __shared__ float r1[4], r2[4];
    int w = tid >> 6;
    if ((tid & 63) == 0) { r1[w] = s1; r2[w] = s2; }
    __syncthreads();
    s1 = r1[0] + r1[1] + r1[2] + r1[3];
    s2 = r2[0] + r2[1] + r2[2] + r2[3];
    float mu = s1 * (1.0f / 1024.0f);
    float var = s2 * (1.0f / 1024.0f) - mu * mu;
    float inv = rsqrtf(var + 1e-5f);
    float y[4];
#pragma unroll
    for (int i = 0; i < 4; i++)
        y[i] = (v[i] - mu) * inv * g[tid * 4 + i] + b[tid * 4 + i];
    unsigned int lo = (unsigned int)f2bf(y[0]) | ((unsigned int)f2bf(y[1]) << 16);
    unsigned int hi = (unsigned int)f2bf(y[2]) | ((unsigned int)f2bf(y[3]) << 16);
    *(uint2*)(out + row * 1024 + tid * 4) = make_uint2(lo, hi);
}

// ------- 128x128 MFMA GEMM (R2-proven 2-phase), for N=1024 outputs (Wo, W2) ----
template <typename OutT, int RELU>
__device__ __forceinline__ void gemm128(
    const ushort_t* __restrict__ A, int lda,
    const ushort_t* __restrict__ Bt, int ldb, int K,
    OutT* __restrict__ C, long cBatch, int ldc,
    const float* __restrict__ bias, const float* __restrict__ resid,
    ushort_t* As, ushort_t* Bs) {   // each [2][128*32]
    int m0 = blockIdx.x * 128, n0 = blockIdx.y * 128;
    int tid = threadIdx.x, lane = tid & 63, w = tid >> 6;
    int ln = lane & 15, quad = lane >> 4;
    int wr = w >> 1, wc = w & 1;
    int lr = lane >> 2, lc = (lane & 3) * 8;

    auto stage = [&](int k0, int buf) {
#pragma unroll
        for (int i = 0; i < 4; i++) {
            int id = w * 4 + i;  // wave-uniform
            int blk = id & 7;
            int row = blk * 16 + lr;
            if (id < 8)
                gll16(A + (long)(m0 + row) * lda + k0 + lc, As + buf * 4096 + blk * 512);
            else
                gll16(Bt + (long)(n0 + row) * ldb + k0 + lc, Bs + buf * 4096 + blk * 512);
        }
    };

    floatx4 acc[4][4];
#pragma unroll
    for (int a = 0; a < 4; a++)
#pragma unroll
        for (int bb = 0; bb < 4; bb++) acc[a][bb] = floatx4{0, 0, 0, 0};

    stage(0, 0);
    int cur = 0;
    for (int k0 = 0; k0 < K; k0 += 32, cur ^= 1) {
        __syncthreads();  // own staged loads drained; other buffer free
        if (k0 + 32 < K) stage(k0 + 32, cur ^ 1);
        const ushort_t* Ab = As + cur * 4096;
        const ushort_t* Bb = Bs + cur * 4096;
        short8 af[4], bf[4];
#pragma unroll
        for (int j = 0; j < 4; j++) {
            af[j] = *(const short8*)(Ab + (wr * 64 + j * 16 + ln) * 32 + quad * 8);
            bf[j] = *(const short8*)(Bb + (wc * 64 + j * 16 + ln) * 32 + quad * 8);
        }
#pragma unroll
        for (int a = 0; a < 4; a++)
#pragma unroll
            for (int bb = 0; bb < 4; bb++)
                acc[a][bb] = __builtin_amdgcn_mfma_f32_16x16x32_bf16(af[a], bf[bb], acc[a][bb], 0, 0, 0);
    }
#pragma unroll
    for (int bb = 0; bb < 4; bb++) {
        int gn = n0 + wc * 64 + bb * 16 + ln;
        float bv = bias ? bias[gn] : 0.0f;
#pragma unroll
        for (int a = 0; a < 4; a++) {
#pragma unroll
            for (int r = 0; r < 4; r++) {
                int gm = m0 + wr * 64 + a * 16 + quad * 4 + r;
                float val = acc[a][bb][r] + bv;
                if (RELU) val = fmaxf(val, 0.0f);
                long off = (long)(gm >> 11) * cBatch + (long)(gm & 2047) * ldc + gn;
                if (resid) val += resid[off];
                if constexpr (sizeof(OutT) == 2)
                    C[off] = (OutT)f2bf(val);
                else
                    C[off] = (OutT)val;
            }
        }
    }
}

__global__ __launch_bounds__(256) void gemm128_f32_kernel(
    const ushort_t* __restrict__ A, int lda, const ushort_t* __restrict__ Bt, int ldb, int K,
    float* __restrict__ C, long cBatch, int ldc,
    const float* __restrict__ bias, const float* __restrict__ resid) {
    __shared__ ushort_t As[2 * 128 * 32];
    __shared__ ushort_t Bs[2 * 128 * 32];
    gemm128<float, 0>(A, lda, Bt, ldb, K, C, cBatch, ldc, bias, resid, As, Bs);
}

// ------- 256x256 MFMA GEMM, BK=64, ONE barrier pair per K-tile ("free-flow" core) -------
// 512 threads = 8 waves (2M x 4N); per-wave output 128x64; LDS 2 bufs x (A 32K + B 32K) = 128K.
// Per K-tile t: issue all 8 staging DMAs for tile t+1 (buf (t+1)&1), then frag reads + 64
// MFMAs on tile t (buf t&1) flow with NO intra-tile barriers — reads and stages touch
// disjoint buffers, so the compiler/HW freely overlaps LDS reads, VMEM issue, and MFMA.
// Tile boundary: vmcnt(0) (drains t+1's loads, issued a full K-tile ~2500cyc ago -> latency
// fully covered) + raw s_barrier (publishes buf (t+1)&1; also guarantees all waves done
// reading buf t&1 before tile t+2 staging overwrites it next iteration).
// LDS rows are 64 elems (128 B, spans all 32 banks). 8-slot XOR swizzle: 16B slot s of row
// holds global slot s ^ ((row>>1)&7), via pre-swizzled global source (gll16 dest linear);
// frag reads compensate with slot ^ ((ln>>1)&7) -> 2 lanes/bank (free, m136).
// MODE 0: C bf16 +bias/relu. MODE 2 (QKV): n<1024 q, n<2048 k, n>=2048 v^T (R2-verified).
template <int RELU, int MODE>
__device__ __forceinline__ void gemm256k64(
    const ushort_t* __restrict__ A, int lda,
    const ushort_t* __restrict__ Bt, int ldb, int K, int ntn,
    ushort_t* __restrict__ C, long cBatch, int ldc,
    const float* __restrict__ bias, ushort_t* lds) {
    int nwg = gridDim.x;
    int wg = ((int)blockIdx.x & 7) * (nwg >> 3) + ((int)blockIdx.x >> 3);  // XCD swizzle
    int m0 = (wg / ntn) * 256, n0 = (wg % ntn) * 256;
    int tid = threadIdx.x, lane = tid & 63, w = tid >> 6;
    int ln = lane & 15, quad = lane >> 4;
    int wm = w >> 2, wn = w & 3;
    int rsw8 = (ln >> 1) & 7;                     // read-side slot swizzle
    // stage-side: per round, this thread covers row (r*64 + srow), 16B slot (lane&7)
    int srow = w * 8 + (lane >> 3);
    int sswz = (w * 4 + (lane >> 4)) & 7;         // == ((srow)>>1)&7 (r*64 contributes 0 mod 8)
    int scol = ((lane & 7) ^ sswz) * 8;           // pre-swizzled source col (elems)

    const ushort_t* pa[4];
    const ushort_t* pb[4];
#pragma unroll
    for (int r = 0; r < 4; r++) {
        pa[r] = A + (long)(m0 + r * 64 + srow) * lda + scol;
        pb[r] = Bt + (long)(n0 + r * 64 + srow) * ldb + scol;
    }
    // buffer layout (elems): buf b at b*32768; A tile at +0 (256 rows x 64), B at +16384
    auto stage = [&](int t) {
        ushort_t* dst = lds + (t & 1) * 32768;
        int wb = w * 512;  // wave-uniform base within round (8 rows x 64 elems)
#pragma unroll
        for (int r = 0; r < 4; r++) gll16(pa[r] + t * 64, dst + r * 4096 + wb);
#pragma unroll
        for (int r = 0; r < 4; r++) gll16(pb[r] + t * 64, dst + 16384 + r * 4096 + wb);
    };

    floatx4 acc[8][4];
#pragma unroll
    for (int m = 0; m < 8; m++)
#pragma unroll
        for (int n = 0; n < 4; n++) acc[m][n] = floatx4{0, 0, 0, 0};

    int NT = K >> 6;
    stage(0);
    asm volatile("s_waitcnt vmcnt(0)" ::: "memory");
    SBAR();

    for (int t = 0; t < NT; ++t) {
        if (t + 1 < NT) stage(t + 1);
        const ushort_t* Ab = lds + (t & 1) * 32768;
        const ushort_t* Bb = Ab + 16384;
#pragma unroll
        for (int ks = 0; ks < 2; ks++) {
            short8 af[8], bf[4];
            int sl = (((ks << 2) | quad) ^ rsw8) << 3;  // swizzled slot -> elem offset
#pragma unroll
            for (int m = 0; m < 8; m++)
                af[m] = *(const short8*)(Ab + (wm * 128 + m * 16 + ln) * 64 + sl);
#pragma unroll
            for (int n = 0; n < 4; n++)
                bf[n] = *(const short8*)(Bb + (wn * 64 + n * 16 + ln) * 64 + sl);
            __builtin_amdgcn_s_setprio(1);
#pragma unroll
            for (int m = 0; m < 8; m++)
#pragma unroll
                for (int n = 0; n < 4; n++)
                    acc[m][n] = __builtin_amdgcn_mfma_f32_16x16x32_bf16(af[m], bf[n], acc[m][n], 0, 0, 0);
            __builtin_amdgcn_s_setprio(0);
        }
        asm volatile("s_waitcnt vmcnt(0)" ::: "memory");
        SBAR();
    }

    // epilogue (verbatim structure from the R3-verified gemm256)
#pragma unroll
    for (int bb = 0; bb < 4; bb++) {
        int gn = n0 + wn * 64 + bb * 16 + ln;
        float bv = bias[gn];
#pragma unroll
        for (int a = 0; a < 8; a++) {
#pragma unroll
            for (int r = 0; r < 4; r++) {
                int gm = m0 + wm * 128 + a * 16 + quad * 4 + r;
                float val = acc[a][bb][r] + bv;
                if (RELU) val = fmaxf(val, 0.0f);
                long off;
                if constexpr (MODE == 2) {
                    int gnl = gn & 1023;
                    if (gn < 2048)  // q or k: [2][B,T,1024] contiguous
                        off = (long)(gn >> 10) * 8388608 + (long)(gm >> 11) * 2097152 +
                              (long)(gm & 2047) * 1024 + gnl;
                    else  // v transposed: [B,H,64,2048] at +16M elems
                        off = 16777216L +
                              ((((long)(gm >> 11)) * 16 + (gnl >> 6)) * 64 + (gnl & 63)) * 2048 +
                              (gm & 2047);
                } else {
                    off = (long)(gm >> 11) * cBatch + (long)(gm & 2047) * ldc + gn;
                }
                C[off] = f2bf(val);
            }
        }
    }
}

__global__ __launch_bounds__(512, 2) void gemm256_qkv_kernel(
    const ushort_t* __restrict__ A, const ushort_t* __restrict__ Bt,
    ushort_t* __restrict__ C, const float* __restrict__ bias) {
    __shared__ ushort_t lds[2 * 32768];
    gemm256k64<0, 2>(A, 1024, Bt, 1024, 1024, 12, C, 0, 0, bias, lds);
}

__global__ __launch_bounds__(512, 2) void gemm256_relu_kernel(
    const ushort_t* __restrict__ A, const ushort_t* __restrict__ Bt,
    ushort_t* __restrict__ C, const float* __restrict__ bias) {
    __shared__ ushort_t lds[2 * 32768];
    gemm256k64<1, 0>(A, 1024, Bt, 1024, 1024, 8, C, 2048L * 2048, 2048, bias, lds);
}

// ---------------- MFMA flash attention v6: LDS-free P via K-row permutation ----------------
// (unchanged from R2: 0 bank conflicts, 32KB LDS; see R2 notes)
__global__ __launch_bounds__(512, 4) void attn_kernel(
    const ushort_t* __restrict__ q, const ushort_t* __restrict__ k,
    const ushort_t* __restrict__ vt, ushort_t* __restrict__ o) {
    __shared__ ushort_t Klds[2 * 4096];       // [buf][s-half][kv slot 64][32]
    __shared__ ushort_t Vlds[2 * 4096];       // [buf][kv-half][d row 64][32]
    int flat = blockIdx.x;
    int bh = (flat & 7) * 8 + (flat >> 6);
    int xt = (flat >> 3) & 7;
    int b = bh >> 4, h = bh & 15;
    int t0 = xt * 256;
    int tid = threadIdx.x, lane = tid & 63, w = tid >> 6;
    int ln = lane & 15, quad = lane >> 4;
    int lr = lane >> 2, lq = lane & 3;
    int bsrc = (lane & 48) + ((lane >> 4) << 2);  // broadcast src: ln' = quad*4+r
    int rsw = (ln >> 1) & 3;                      // read-side K/V slot swizzle
    int ssw = (lr >> 1) & 3;                      // stage-side (source col) swizzle

    const ushort_t* qbase = q + ((long)b * 2048 + t0 + w * 32) * 1024 + h * 64;
    short8 qf[2][2];
#pragma unroll
    for (int sub = 0; sub < 2; sub++)
#pragma unroll
        for (int s = 0; s < 2; s++) {
            ushortx8 t = *(const ushortx8*)(qbase + (long)(sub * 16 + ln) * 1024 + s * 32 + quad * 8);
#pragma unroll
            for (int j = 0; j < 8; j++) qf[sub][s][j] = (short)f2bf(b2f(t[j]) * 8.0f);
        }

    floatx4 O[2][4];
    float m_i[2] = {-1e30f, -1e30f}, l_i[2] = {0.0f, 0.0f};
#pragma unroll
    for (int sub = 0; sub < 2; sub++)
#pragma unroll
        for (int i = 0; i < 4; i++) O[sub][i] = floatx4{0, 0, 0, 0};

    long krow0 = (long)b * 2048 * 1024 + h * 64;
    const ushort_t* vbase = vt + (long)bh * 64 * 2048;

    auto stage = [&](int kv0, int buf) {
#pragma unroll
        for (int i = 0; i < 2; i++) {
            int id = w * 2 + i;  // 0..15: 8 K-quarters then 8 V-quarters
            int s = (id >> 2) & 1, qt = id & 3;
            int cs = ((lq ^ ssw) << 3);
            if (id < 8) {
                int prow = ((qt >> 1) << 5) + ((lr >> 2) << 3) + ((qt & 1) << 2) + (lr & 3);
                gll16(k + krow0 + (long)(kv0 + prow) * 1024 + s * 32 + cs,
                      Klds + buf * 4096 + s * 2048 + qt * 512);
            } else {
                int row = qt * 16 + lr;  // d row
                gll16(vbase + (long)row * 2048 + kv0 + s * 32 + cs,
                      Vlds + buf * 4096 + s * 2048 + qt * 512);
            }
        }
    };

    stage(0, 0);
    int cur = 0;
    for (int t32 = 0; t32 < 32; t32++, cur ^= 1) {
        __syncthreads();
        if (t32 < 31) stage((t32 + 1) * 64, cur ^ 1);
        const ushort_t* Kb = Klds + cur * 4096;
        const ushort_t* Vb = Vlds + cur * 4096;

        floatx4 Z[2][4];
#pragma unroll
        for (int sub = 0; sub < 2; sub++)
#pragma unroll
            for (int nc = 0; nc < 4; nc++) Z[sub][nc] = floatx4{0, 0, 0, 0};
#pragma unroll
        for (int s = 0; s < 2; s++)
#pragma unroll
            for (int nc = 0; nc < 4; nc++) {
                short8 kf = *(const short8*)(Kb + s * 2048 + (nc * 16 + ln) * 32 + ((quad ^ rsw) << 3));
                Z[0][nc] = __builtin_amdgcn_mfma_f32_16x16x32_bf16(kf, qf[0][s], Z[0][nc], 0, 0, 0);
                Z[1][nc] = __builtin_amdgcn_mfma_f32_16x16x32_bf16(kf, qf[1][s], Z[1][nc], 0, 0, 0);
            }

        float alpha[2];
        short8 pf[2][2];
#pragma unroll
        for (int sub = 0; sub < 2; sub++) {
            float mx = -1e30f;
#pragma unroll
            for (int nc = 0; nc < 4; nc++)
#pragma unroll
                for (int r = 0; r < 4; r++) mx = fmaxf(mx, Z[sub][nc][r]);
            mx = fmaxf(mx, __shfl_xor(mx, 16));
            mx = fmaxf(mx, __shfl_xor(mx, 32));
            float nm = fmaxf(m_i[sub], mx);
            alpha[sub] = __expf(m_i[sub] - nm);
            m_i[sub] = nm;
            float rs = 0.0f;
#pragma unroll
            for (int s = 0; s < 2; s++) {
                float a0 = __expf(Z[sub][2 * s][0] - nm), a1 = __expf(Z[sub][2 * s][1] - nm);
                float a2 = __expf(Z[sub][2 * s][2] - nm), a3 = __expf(Z[sub][2 * s][3] - nm);
                float b0 = __expf(Z[sub][2 * s + 1][0] - nm), b1 = __expf(Z[sub][2 * s + 1][1] - nm);
                float b2 = __expf(Z[sub][2 * s + 1][2] - nm), b3 = __expf(Z[sub][2 * s + 1][3] - nm);
                rs += ((a0 + a1) + (a2 + a3)) + ((b0 + b1) + (b2 + b3));
                union { unsigned int u[4]; short8 v; } pu;
                pu.u[0] = cvtpk(a0, a1);
                pu.u[1] = cvtpk(a2, a3);
                pu.u[2] = cvtpk(b0, b1);
                pu.u[3] = cvtpk(b2, b3);
                pf[sub][s] = pu.v;
            }
            rs += __shfl_xor(rs, 16);
            rs += __shfl_xor(rs, 32);
            l_i[sub] = l_i[sub] * alpha[sub] + rs;
        }
#pragma unroll
        for (int sub = 0; sub < 2; sub++)
#pragma unroll
            for (int r = 0; r < 4; r++) {
                float ar = __shfl(alpha[sub], bsrc + r);
#pragma unroll
                for (int dc = 0; dc < 4; dc++) O[sub][dc][r] *= ar;
            }
#pragma unroll
        for (int s = 0; s < 2; s++)
#pragma unroll
            for (int dc = 0; dc < 4; dc++) {
                short8 vf = *(const short8*)(Vb + s * 2048 + (dc * 16 + ln) * 32 + ((quad ^ rsw) << 3));
                O[0][dc] = __builtin_amdgcn_mfma_f32_16x16x32_bf16(pf[0][s], vf, O[0][dc], 0, 0, 0);
                O[1][dc] = __builtin_amdgcn_mfma_f32_16x16x32_bf16(pf[1][s], vf, O[1][dc], 0, 0, 0);
            }
    }
#pragma unroll
    for (int sub = 0; sub < 2; sub++)
#pragma unroll
        for (int r = 0; r < 4; r++) {
            float inv = 1.0f / __shfl(l_i[sub], bsrc + r);
            int t = t0 + w * 32 + sub * 16 + quad * 4 + r;
            ushort_t* orow = o + ((long)b * 2048 + t) * 1024 + h * 64;
#pragma unroll
            for (int dc = 0; dc < 4; dc++) orow[dc * 16 + ln] = f2bf(O[sub][dc][r] * inv);
        }
}

extern "C" void kernel_launch(void* const* d_in, const int* in_sizes, int n_in,
                              void* d_out, int out_size, void* d_ws, size_t ws_size,
                              hipStream_t stream) {
    const float* x   = (const float*)d_in[0];
    const float* Wq  = (const float*)d_in[1];
    const float* bq  = (const float*)d_in[2];
    const float* Wk  = (const float*)d_in[3];
    const float* bk  = (const float*)d_in[4];
    const float* Wv  = (const float*)d_in[5];
    const float* bv  = (const float*)d_in[6];
    const float* Wo  = (const float*)d_in[7];
    const float* bo  = (const float*)d_in[8];
    const float* g1  = (const float*)d_in[9];
    const float* be1 = (const float*)d_in[10];
    const float* g2  = (const float*)d_in[11];
    const float* be2 = (const float*)d_in[12];
    const float* W1  = (const float*)d_in[13];
    const float* b1  = (const float*)d_in[14];
    const float* W2  = (const float*)d_in[15];
    const float* b2  = (const float*)d_in[16];
    float* out = (float*)d_out;

    const long MB = 1 << 20;
    char* w = (char*)d_ws;
    ushort_t* xn  = (ushort_t*)(w);            // [8192,1024] bf16; reused as attn output o
    float*    x2  = (float*)(w + 16 * MB);     // [8192,1024] f32 (first 12KB doubles as biasCat)
    ushort_t* qb  = (ushort_t*)(w + 48 * MB);  // [B,T,C] bf16; kb,vtb contiguous after
    ushort_t* kb  = (ushort_t*)(w + 64 * MB);  // [B,T,C] bf16
    ushort_t* vtb = (ushort_t*)(w + 80 * MB);  // [B,H,DH,T] bf16
    ushort_t* xn2 = qb;                        // alias (qb dead after attention)
    ushort_t* h1  = (ushort_t*)(w + 64 * MB);  // [8192,2048] bf16 (kb/vtb dead)
    ushort_t* WqT = (ushort_t*)(w + 96 * MB);  // [H,DH,C]; WqT/WkT/WvT contiguous = QKV B^T
    ushort_t* WkT = (ushort_t*)(w + 98 * MB);
    ushort_t* WvT = (ushort_t*)(w + 100 * MB);
    ushort_t* WoT = (ushort_t*)(w + 102 * MB); // [C,C]^T
    ushort_t* W1T = (ushort_t*)(w + 104 * MB); // [DFF,C]
    ushort_t* W2T = (ushort_t*)(w + 112 * MB); // [C,DFF]  (ends at 120 MB)
    float* biasCat = x2;                       // 3072 floats, dead before Wo writes x2

    dim3 tb(32, 8);
    transpose_kernel<<<dim3(32, 2, 16), tb, 0, stream>>>(Wq, WqT, 1024, 64);
    transpose_kernel<<<dim3(32, 2, 16), tb, 0, stream>>>(Wk, WkT, 1024, 64);
    transpose_kernel<<<dim3(32, 2, 16), tb, 0, stream>>>(Wv, WvT, 1024, 64);
    transpose_kernel<<<dim3(32, 32, 1), tb, 0, stream>>>(Wo, WoT, 1024, 1024);
    transpose_kernel<<<dim3(32, 128, 1), tb, 0, stream>>>(W1, W1T, 1024, 4096);
    transpose_kernel<<<dim3(128, 32, 1), tb, 0, stream>>>(W2, W2T, 4096, 1024);
    concat_bias_kernel<<<12, 256, 0, stream>>>(bq, bk, bv, biasCat);

    ln_kernel<<<8192, 256, 0, stream>>>(x, xn, g1, be1);
    // fused QKV (free-flow 256x256 BK=64 core): q,k -> [2][B,T,C] at qb; v -> [B,H,DH,T] at vtb
    gemm256_qkv_kernel<<<384, 512, 0, stream>>>(xn, WqT, qb, biasCat);
    attn_kernel<<<512, 512, 0, stream>>>(qb, kb, vtb, xn /* o */);
    // x2 = x + o @ Wo + bo   (fp32 out)
    gemm128_f32_kernel<<<dim3(64, 8), 256, 0, stream>>>(xn, 1024, WoT, 1024, 1024,
                                                        x2, 2048L * 1024, 1024, bo, x);
    ln_kernel<<<8192, 256, 0, stream>>>((const float*)x2, xn2, g2, be2);
    // FFN in two DFF=2048 halves (ws budget); W1 on the free-flow core
    gemm256_relu_kernel<<<256, 512, 0, stream>>>(xn2, W1T, h1, b1);
    gemm128_f32_kernel<<<dim3(64, 8), 256, 0, stream>>>(
        h1, 2048, W2T, 4096, 2048, out, 2048L * 1024, 1024, b2, x2);
    gemm256_relu_kernel<<<256, 512, 0, stream>>>(xn2, W1T + 2048L * 1024, h1, b1 + 2048);
    gemm128_f32_kernel<<<dim3(64, 8), 256, 0, stream>>>(
        h1, 2048, W2T + 2048, 4096, 2048, out, 2048L * 1024, 1024, nullptr, out);
}